// Round 6
// baseline (299.917 us; speedup 1.0000x reference)
//
#include <hip/hip_runtime.h>

#define N_NODES 50000
#define N_EDGES 600000
#define D 128
#define K3 (3 * D)

typedef __attribute__((ext_vector_type(8))) short short8;
typedef __attribute__((ext_vector_type(4))) float floatx4;
typedef __attribute__((ext_vector_type(8))) unsigned short ushort8;

static __device__ __forceinline__ unsigned short f2bf(float f) {
    unsigned u = __float_as_uint(f);
    u += 0x7fff + ((u >> 16) & 1);  // RNE
    return (unsigned short)(u >> 16);
}
static __device__ __forceinline__ float bf2f(unsigned short s) {
    return __uint_as_float(((unsigned)s) << 16);
}

// ---------------- fused setup: convert_x | convert_w | hist ----------------
// blocks [0,3125): x->bf16 into feats[:,0:128]
// blocks [3125,3149): W->frag-ordered Wr
// blocks [3149,5493): histogram of dst into counts
__global__ __launch_bounds__(256) void setup_kernel(const float* __restrict__ x,
                                                    const float* __restrict__ W,
                                                    const int* __restrict__ dst,
                                                    unsigned short* __restrict__ feats,
                                                    unsigned short* __restrict__ Wr,
                                                    int* __restrict__ counts) {
    const int b = blockIdx.x;
    const int tid = threadIdx.x;
    if (b < 3125) {
        unsigned t = b * 256 + tid;  // exactly 50000*16
        unsigned n = t >> 4;
        unsigned c = (t & 15u) << 3;
        const float4 v0 = *(const float4*)(x + (size_t)n * D + c);
        const float4 v1 = *(const float4*)(x + (size_t)n * D + c + 4);
        ushort8 o;
        o[0] = f2bf(v0.x); o[1] = f2bf(v0.y); o[2] = f2bf(v0.z); o[3] = f2bf(v0.w);
        o[4] = f2bf(v1.x); o[5] = f2bf(v1.y); o[6] = f2bf(v1.z); o[7] = f2bf(v1.w);
        *(ushort8*)(feats + (size_t)n * K3 + c) = o;
    } else if (b < 3149) {
        unsigned id = (b - 3125) * 256 + tid;  // exactly 6144 chunks
        unsigned ks = id >> 9;
        unsigned t8 = (id >> 6) & 7u;
        unsigned lane = id & 63u;
        unsigned c = lane & 15u;
        unsigned q = lane >> 4;
        unsigned row = 16u * t8 + c;
        unsigned k = ks * 32u + q * 8u;
        const float4 v0 = *(const float4*)(W + (size_t)row * K3 + k);
        const float4 v1 = *(const float4*)(W + (size_t)row * K3 + k + 4);
        ushort8 o;
        o[0] = f2bf(v0.x); o[1] = f2bf(v0.y); o[2] = f2bf(v0.z); o[3] = f2bf(v0.w);
        o[4] = f2bf(v1.x); o[5] = f2bf(v1.y); o[6] = f2bf(v1.z); o[7] = f2bf(v1.w);
        *(ushort8*)(Wr + (size_t)id * 8) = o;
    } else {
        int e = (b - 3149) * 256 + tid;
        if (e < N_EDGES) atomicAdd(&counts[dst[e]], 1);
    }
}

// ---------------- single-block scan v2 ----------------
// 1024 threads; thread t serially scans counts[49t..49t+49) in registers,
// then two-level (shuffle + LDS) scan of the 1024 thread totals.
#define CHUNK 49
__global__ __launch_bounds__(1024) void scan_kernel(const int* __restrict__ counts,
                                                    int* __restrict__ off,
                                                    int* __restrict__ cursor) {
    __shared__ int tsum[16];
    const int tid = threadIdx.x;
    const int lane = tid & 63, wid = tid >> 6;
    const int start = tid * CHUNK;
    int vals[CHUNK];
    int s = 0;
#pragma unroll
    for (int j = 0; j < CHUNK; ++j) {
        int i = start + j;
        int v = (i < N_NODES) ? counts[i] : 0;
        vals[j] = s;  // exclusive within thread
        s += v;
    }
    int x = s;
#pragma unroll
    for (int d = 1; d < 64; d <<= 1) {
        int u = __shfl_up(x, d);
        if (lane >= d) x += u;
    }
    if (lane == 63) tsum[wid] = x;
    __syncthreads();
    int base = 0;
    for (int w = 0; w < wid; ++w) base += tsum[w];
    int texcl = base + x - s;
#pragma unroll
    for (int j = 0; j < CHUNK; ++j) {
        int i = start + j;
        if (i < N_NODES) {
            int e = texcl + vals[j];
            off[i] = e;
            cursor[i] = e;
        }
    }
    if (tid == 0) off[N_NODES] = N_EDGES;
}

// ---------------- CSR fill ----------------
__global__ __launch_bounds__(256) void fill_kernel(const int* __restrict__ src,
                                                   const int* __restrict__ dst,
                                                   int* __restrict__ cursor,
                                                   int* __restrict__ csr_src) {
    int e = blockIdx.x * blockDim.x + threadIdx.x;
    if (e < N_EDGES) {
        int pos = atomicAdd(&cursor[dst[e]], 1);
        csr_src[pos] = src[e];
    }
}

// ---------------- bf16 gather-mean, one WAVE per node ----------------
// lane = slot*16 + colchunk: slot s in [0,4) owns edges e0+s, e0+s+4, ...;
// colchunk owns 8 bf16 (16 B). 4 independent row-loads in flight per iteration.
__global__ __launch_bounds__(256) void gather_kernel(unsigned short* __restrict__ feats,
                                                     const int* __restrict__ off,
                                                     const int* __restrict__ csr_src,
                                                     int inCol, int outCol) {
    unsigned n = (blockIdx.x * 256 + threadIdx.x) >> 6;
    if (n >= N_NODES) return;
    const int lane = threadIdx.x & 63;
    const int s = lane >> 4;
    const unsigned c = (lane & 15u) << 3;
    const unsigned short* fin = feats + inCol + c;
    const int2 ee = *(const int2*)(off + n);
    const int e0 = ee.x, e1 = ee.y;
    float acc[8] = {0.f, 0.f, 0.f, 0.f, 0.f, 0.f, 0.f, 0.f};
    for (int e = e0 + s; e < e1; e += 16) {
        const int i1 = e + 4, i2 = e + 8, i3 = e + 12;
        int s0 = csr_src[e];
        int s1 = (i1 < e1) ? csr_src[i1] : s0;
        int s2 = (i2 < e1) ? csr_src[i2] : s0;
        int s3 = (i3 < e1) ? csr_src[i3] : s0;
        float m1 = (i1 < e1) ? 1.f : 0.f;
        float m2 = (i2 < e1) ? 1.f : 0.f;
        float m3 = (i3 < e1) ? 1.f : 0.f;
        ushort8 v0 = *(const ushort8*)(fin + (size_t)s0 * K3);
        ushort8 v1 = *(const ushort8*)(fin + (size_t)s1 * K3);
        ushort8 v2 = *(const ushort8*)(fin + (size_t)s2 * K3);
        ushort8 v3 = *(const ushort8*)(fin + (size_t)s3 * K3);
#pragma unroll
        for (int j = 0; j < 8; ++j) {
            float t0 = bf2f(v0[j]) + m1 * bf2f(v1[j]);
            float t1 = m2 * bf2f(v2[j]) + m3 * bf2f(v3[j]);
            acc[j] += t0 + t1;
        }
    }
#pragma unroll
    for (int j = 0; j < 8; ++j) {
        acc[j] += __shfl_xor(acc[j], 16);
        acc[j] += __shfl_xor(acc[j], 32);
    }
    if (s == 0) {
        float inv = 1.0f / fmaxf((float)(e1 - e0), 1.0f);
        ushort8 o;
#pragma unroll
        for (int j = 0; j < 8; ++j) o[j] = f2bf(acc[j] * inv);
        *(ushort8*)(feats + (size_t)n * K3 + outCol + c) = o;
    }
}

// ---------------- bf16 MFMA GEMM: out[N,128] = feats[N,384] @ W^T + b ----------------
// 2 waves/block (128 thr); wave tile = 64 rows x 128 cols (4 rowblocks x 8 colblocks).
// B:MFMA = 1:4; B-frags from frag-ordered Wr (coalesced, L2-resident).
__global__ __launch_bounds__(128, 2) void gemm_mfma_kernel(const unsigned short* __restrict__ feats,
                                                           const unsigned short* __restrict__ Wr,
                                                           const float* __restrict__ bias,
                                                           float* __restrict__ out) {
    const int tid = threadIdx.x;
    const int wave = tid >> 6;
    const int lane = tid & 63;
    const int col = lane & 15;
    const int quad = lane >> 4;
    const int mbase = blockIdx.x * 128 + wave * 64;

    const unsigned short* aptr[4];
#pragma unroll
    for (int rb = 0; rb < 4; ++rb) {
        int r = mbase + rb * 16 + col;
        if (r >= N_NODES) r = N_NODES - 1;  // clamp loads; stores guarded
        aptr[rb] = feats + (size_t)r * K3 + quad * 8;
    }
    const unsigned short* wptr = Wr + (size_t)lane * 8;

    floatx4 acc[4][8];
#pragma unroll
    for (int rb = 0; rb < 4; ++rb)
#pragma unroll
        for (int t = 0; t < 8; ++t) acc[rb][t] = (floatx4){0.f, 0.f, 0.f, 0.f};

#pragma unroll
    for (int ks = 0; ks < 12; ++ks) {
        short8 a[4];
#pragma unroll
        for (int rb = 0; rb < 4; ++rb) a[rb] = *(const short8*)(aptr[rb] + ks * 32);
        short8 b[8];
#pragma unroll
        for (int t = 0; t < 8; ++t)
            b[t] = *(const short8*)(wptr + (size_t)(ks * 8 + t) * 512);
#pragma unroll
        for (int t = 0; t < 8; ++t)
#pragma unroll
            for (int rb = 0; rb < 4; ++rb)
                acc[rb][t] = __builtin_amdgcn_mfma_f32_16x16x32_bf16(a[rb], b[t], acc[rb][t], 0, 0, 0);
    }

#pragma unroll
    for (int t = 0; t < 8; ++t) {
        float bv = bias[t * 16 + col];
#pragma unroll
        for (int rb = 0; rb < 4; ++rb)
#pragma unroll
            for (int r = 0; r < 4; ++r) {
                int o = mbase + rb * 16 + quad * 4 + r;
                if (o < N_NODES) out[(size_t)o * D + t * 16 + col] = acc[rb][t][r] + bv;
            }
    }
}

extern "C" void kernel_launch(void* const* d_in, const int* in_sizes, int n_in,
                              void* d_out, int out_size, void* d_ws, size_t ws_size,
                              hipStream_t stream) {
    const float* x = (const float*)d_in[0];
    const int* ei = (const int*)d_in[1];
    const float* W = (const float*)d_in[2];
    const float* b = (const float*)d_in[3];
    float* out = (float*)d_out;
    const int* src = ei;            // edge_index[0,:]
    const int* dst = ei + N_EDGES;  // edge_index[1,:]

    // workspace layout:
    //   feats   [N][384] bf16  38.4 MB (cols 0-127 = x, 128-255 = hop1, 256-383 = hop2)
    //   Wr      frag-ordered W bf16, 6144 chunks x 16 B
    //   off     [N+1] i32 | cursor [N] i32 | csr_src [E] i32
    unsigned short* feats = (unsigned short*)d_ws;
    unsigned short* Wr = feats + (size_t)N_NODES * K3;
    int* off = (int*)(Wr + (size_t)D * K3);
    int* cursor = off + (N_NODES + 1);
    int* csr_src = cursor + N_NODES;

    hipMemsetAsync(cursor, 0, (size_t)N_NODES * sizeof(int), stream);

    setup_kernel<<<5493, 256, 0, stream>>>(x, W, dst, feats, Wr, cursor);
    scan_kernel<<<1, 1024, 0, stream>>>(cursor, off, cursor);
    fill_kernel<<<(N_EDGES + 255) / 256, 256, 0, stream>>>(src, dst, cursor, csr_src);

    const int ggrid = (N_NODES * 64 + 255) / 256;  // one wave per node
    gather_kernel<<<ggrid, 256, 0, stream>>>(feats, off, csr_src, 0, D);
    gather_kernel<<<ggrid, 256, 0, stream>>>(feats, off, csr_src, D, 2 * D);

    gemm_mfma_kernel<<<(N_NODES + 127) / 128, 128, 0, stream>>>(feats, Wr, b, out);
}

// Round 7
// 221.709 us; speedup vs baseline: 1.3528x; 1.3528x over previous
//
#include <hip/hip_runtime.h>

#define N_NODES 50000
#define N_EDGES 600000
#define D 128
#define K3 (3 * D)

typedef __attribute__((ext_vector_type(8))) short short8;
typedef __attribute__((ext_vector_type(4))) float floatx4;
typedef __attribute__((ext_vector_type(8))) unsigned short ushort8;

static __device__ __forceinline__ unsigned short f2bf(float f) {
    unsigned u = __float_as_uint(f);
    u += 0x7fff + ((u >> 16) & 1);  // RNE
    return (unsigned short)(u >> 16);
}
static __device__ __forceinline__ float bf2f(unsigned short s) {
    return __uint_as_float(((unsigned)s) << 16);
}

// ---------------- fused setup: convert_x | convert_w | hist ----------------
__global__ __launch_bounds__(256) void setup_kernel(const float* __restrict__ x,
                                                    const float* __restrict__ W,
                                                    const int* __restrict__ dst,
                                                    unsigned short* __restrict__ feats,
                                                    unsigned short* __restrict__ Wr,
                                                    int* __restrict__ counts) {
    const int b = blockIdx.x;
    const int tid = threadIdx.x;
    if (b < 3125) {
        unsigned t = b * 256 + tid;  // exactly 50000*16
        unsigned n = t >> 4;
        unsigned c = (t & 15u) << 3;
        const float4 v0 = *(const float4*)(x + (size_t)n * D + c);
        const float4 v1 = *(const float4*)(x + (size_t)n * D + c + 4);
        ushort8 o;
        o[0] = f2bf(v0.x); o[1] = f2bf(v0.y); o[2] = f2bf(v0.z); o[3] = f2bf(v0.w);
        o[4] = f2bf(v1.x); o[5] = f2bf(v1.y); o[6] = f2bf(v1.z); o[7] = f2bf(v1.w);
        *(ushort8*)(feats + (size_t)n * K3 + c) = o;
    } else if (b < 3149) {
        unsigned id = (b - 3125) * 256 + tid;  // exactly 6144 chunks
        unsigned ks = id >> 9;
        unsigned t8 = (id >> 6) & 7u;
        unsigned lane = id & 63u;
        unsigned c = lane & 15u;
        unsigned q = lane >> 4;
        unsigned row = 16u * t8 + c;
        unsigned k = ks * 32u + q * 8u;
        const float4 v0 = *(const float4*)(W + (size_t)row * K3 + k);
        const float4 v1 = *(const float4*)(W + (size_t)row * K3 + k + 4);
        ushort8 o;
        o[0] = f2bf(v0.x); o[1] = f2bf(v0.y); o[2] = f2bf(v0.z); o[3] = f2bf(v0.w);
        o[4] = f2bf(v1.x); o[5] = f2bf(v1.y); o[6] = f2bf(v1.z); o[7] = f2bf(v1.w);
        *(ushort8*)(Wr + (size_t)id * 8) = o;
    } else {
        int e = (b - 3149) * 256 + tid;
        if (e < N_EDGES) atomicAdd(&counts[dst[e]], 1);
    }
}

// ---------------- 3-phase scan (Round-5 proven) ----------------
__global__ __launch_bounds__(256) void bsum_kernel(const int* __restrict__ counts,
                                                   int* __restrict__ bsum) {
    __shared__ int wsum[4];
    int tid = threadIdx.x;
    int i = blockIdx.x * 256 + tid;
    int v = (i < N_NODES) ? counts[i] : 0;
#pragma unroll
    for (int d = 32; d >= 1; d >>= 1) v += __shfl_xor(v, d);
    if ((tid & 63) == 0) wsum[tid >> 6] = v;
    __syncthreads();
    if (tid == 0) bsum[blockIdx.x] = wsum[0] + wsum[1] + wsum[2] + wsum[3];
}

__global__ __launch_bounds__(256) void scan_bsum_kernel(const int* __restrict__ bsum,
                                                        int* __restrict__ bexcl,
                                                        int* __restrict__ off, int nb) {
    __shared__ int wsum[4];
    int tid = threadIdx.x;
    int lane = tid & 63, wid = tid >> 6;
    int v = (tid < nb) ? bsum[tid] : 0;
    int x = v;
#pragma unroll
    for (int d = 1; d < 64; d <<= 1) {
        int u = __shfl_up(x, d);
        if (lane >= d) x += u;
    }
    if (lane == 63) wsum[wid] = x;
    __syncthreads();
    int prefix = 0;
    for (int w = 0; w < wid; ++w) prefix += wsum[w];
    if (tid < nb) bexcl[tid] = prefix + x - v;
    if (tid == 0) off[N_NODES] = N_EDGES;
}

__global__ __launch_bounds__(256) void scan_final_kernel(const int* __restrict__ counts,
                                                         const int* __restrict__ bexcl,
                                                         int* __restrict__ off,
                                                         int* __restrict__ cursor) {
    __shared__ int wsum[4];
    int tid = threadIdx.x;
    int lane = tid & 63, wid = tid >> 6;
    int i = blockIdx.x * 256 + tid;
    int v = (i < N_NODES) ? counts[i] : 0;
    int x = v;
#pragma unroll
    for (int d = 1; d < 64; d <<= 1) {
        int u = __shfl_up(x, d);
        if (lane >= d) x += u;
    }
    if (lane == 63) wsum[wid] = x;
    __syncthreads();
    int prefix = 0;
    for (int w = 0; w < wid; ++w) prefix += wsum[w];
    if (i < N_NODES) {
        int excl = bexcl[blockIdx.x] + prefix + x - v;
        off[i] = excl;
        cursor[i] = excl;
    }
}

// ---------------- CSR fill ----------------
__global__ __launch_bounds__(256) void fill_kernel(const int* __restrict__ src,
                                                   const int* __restrict__ dst,
                                                   int* __restrict__ cursor,
                                                   int* __restrict__ csr_src) {
    int e = blockIdx.x * blockDim.x + threadIdx.x;
    if (e < N_EDGES) {
        int pos = atomicAdd(&cursor[dst[e]], 1);
        csr_src[pos] = src[e];
    }
}

// ---------------- bf16 gather-mean, one WAVE per node ----------------
// lane = slot*16 + colchunk; slot s owns contiguous edge groups [gbase+4s, gbase+4s+4)
// where gbase = e0 & ~3 (16-B-aligned int4 index loads; validity masked on both
// ends; indices clamped so padded/garbage reads stay in-bounds).
__global__ __launch_bounds__(256) void gather_kernel(unsigned short* __restrict__ feats,
                                                     const int* __restrict__ off,
                                                     const int* __restrict__ csr_src,
                                                     int inCol, int outCol) {
    unsigned n = (blockIdx.x * 256 + threadIdx.x) >> 6;
    if (n >= N_NODES) return;
    const int lane = threadIdx.x & 63;
    const int s = lane >> 4;
    const unsigned c = (lane & 15u) << 3;
    const unsigned short* fin = feats + inCol + c;
    const int2 ee = *(const int2*)(off + n);
    const int e0 = ee.x, e1 = ee.y;
    float acc[8] = {0.f, 0.f, 0.f, 0.f, 0.f, 0.f, 0.f, 0.f};
    for (int base = (e0 & ~3) + s * 4; base < e1; base += 16) {
        int4 idx = *(const int4*)(csr_src + base);  // aligned; pad makes OOB safe
        float m0 = (base >= e0 && base < e1) ? 1.f : 0.f;
        float m1 = (base + 1 >= e0 && base + 1 < e1) ? 1.f : 0.f;
        float m2 = (base + 2 >= e0 && base + 2 < e1) ? 1.f : 0.f;
        float m3 = (base + 3 >= e0 && base + 3 < e1) ? 1.f : 0.f;
        int s0 = min(max(idx.x, 0), N_NODES - 1);
        int s1 = min(max(idx.y, 0), N_NODES - 1);
        int s2 = min(max(idx.z, 0), N_NODES - 1);
        int s3 = min(max(idx.w, 0), N_NODES - 1);
        ushort8 v0 = *(const ushort8*)(fin + (size_t)s0 * K3);
        ushort8 v1 = *(const ushort8*)(fin + (size_t)s1 * K3);
        ushort8 v2 = *(const ushort8*)(fin + (size_t)s2 * K3);
        ushort8 v3 = *(const ushort8*)(fin + (size_t)s3 * K3);
#pragma unroll
        for (int j = 0; j < 8; ++j) {
            float t0 = m0 * bf2f(v0[j]) + m1 * bf2f(v1[j]);
            float t1 = m2 * bf2f(v2[j]) + m3 * bf2f(v3[j]);
            acc[j] += t0 + t1;
        }
    }
#pragma unroll
    for (int j = 0; j < 8; ++j) {
        acc[j] += __shfl_xor(acc[j], 16);
        acc[j] += __shfl_xor(acc[j], 32);
    }
    if (s == 0) {
        float inv = 1.0f / fmaxf((float)(e1 - e0), 1.0f);
        ushort8 o;
#pragma unroll
        for (int j = 0; j < 8; ++j) o[j] = f2bf(acc[j] * inv);
        *(ushort8*)(feats + (size_t)n * K3 + outCol + c) = o;
    }
}

// ---------------- bf16 MFMA GEMM (Round-5 proven): 4 waves, 32-row wave tile ----
__global__ __launch_bounds__(256) void gemm_mfma_kernel(const unsigned short* __restrict__ feats,
                                                        const unsigned short* __restrict__ Wr,
                                                        const float* __restrict__ bias,
                                                        float* __restrict__ out) {
    const int tid = threadIdx.x;
    const int wave = tid >> 6;
    const int lane = tid & 63;
    const int col = lane & 15;
    const int quad = lane >> 4;
    const int mbase = blockIdx.x * 128 + wave * 32;

    int r0 = mbase + col;
    int r1 = mbase + 16 + col;
    if (r0 >= N_NODES) r0 = N_NODES - 1;
    if (r1 >= N_NODES) r1 = N_NODES - 1;
    const unsigned short* aptr0 = feats + (size_t)r0 * K3 + quad * 8;
    const unsigned short* aptr1 = feats + (size_t)r1 * K3 + quad * 8;
    const unsigned short* wptr = Wr + (size_t)lane * 8;

    floatx4 acc0[8], acc1[8];
#pragma unroll
    for (int t = 0; t < 8; ++t) {
        acc0[t] = (floatx4){0.f, 0.f, 0.f, 0.f};
        acc1[t] = (floatx4){0.f, 0.f, 0.f, 0.f};
    }

#pragma unroll
    for (int ks = 0; ks < 12; ++ks) {
        short8 a0 = *(const short8*)(aptr0 + ks * 32);
        short8 a1 = *(const short8*)(aptr1 + ks * 32);
        short8 b[8];
#pragma unroll
        for (int t = 0; t < 8; ++t)
            b[t] = *(const short8*)(wptr + (size_t)(ks * 8 + t) * 512);
#pragma unroll
        for (int t = 0; t < 8; ++t) {
            acc0[t] = __builtin_amdgcn_mfma_f32_16x16x32_bf16(a0, b[t], acc0[t], 0, 0, 0);
            acc1[t] = __builtin_amdgcn_mfma_f32_16x16x32_bf16(a1, b[t], acc1[t], 0, 0, 0);
        }
    }

#pragma unroll
    for (int t = 0; t < 8; ++t) {
        float bv = bias[t * 16 + col];
#pragma unroll
        for (int r = 0; r < 4; ++r) {
            int o0 = mbase + quad * 4 + r;
            int o1 = mbase + 16 + quad * 4 + r;
            if (o0 < N_NODES) out[(size_t)o0 * D + t * 16 + col] = acc0[t][r] + bv;
            if (o1 < N_NODES) out[(size_t)o1 * D + t * 16 + col] = acc1[t][r] + bv;
        }
    }
}

extern "C" void kernel_launch(void* const* d_in, const int* in_sizes, int n_in,
                              void* d_out, int out_size, void* d_ws, size_t ws_size,
                              hipStream_t stream) {
    const float* x = (const float*)d_in[0];
    const int* ei = (const int*)d_in[1];
    const float* W = (const float*)d_in[2];
    const float* b = (const float*)d_in[3];
    float* out = (float*)d_out;
    const int* src = ei;            // edge_index[0,:]
    const int* dst = ei + N_EDGES;  // edge_index[1,:]

    // workspace layout:
    //   feats   [N][384] bf16  38.4 MB (cols 0-127 = x, 128-255 = hop1, 256-383 = hop2)
    //   Wr      frag-ordered W bf16, 6144 chunks x 16 B
    //   off     [N+1] i32 | cursor [N] i32 | bsum/bexcl | csr_src [E+16] i32 (padded)
    unsigned short* feats = (unsigned short*)d_ws;
    unsigned short* Wr = feats + (size_t)N_NODES * K3;
    int* off = (int*)(Wr + (size_t)D * K3);
    int* cursor = off + (N_NODES + 1);
    int* bsum = cursor + N_NODES;
    int* bexcl = bsum + 256;
    int* csr_src = bexcl + 256;  // E + 16 pad; reads clamped, contributions masked

    const int NB = (N_NODES + 255) / 256;  // 196

    hipMemsetAsync(cursor, 0, (size_t)N_NODES * sizeof(int), stream);

    setup_kernel<<<5493, 256, 0, stream>>>(x, W, dst, feats, Wr, cursor);
    bsum_kernel<<<NB, 256, 0, stream>>>(cursor, bsum);
    scan_bsum_kernel<<<1, 256, 0, stream>>>(bsum, bexcl, off, NB);
    scan_final_kernel<<<NB, 256, 0, stream>>>(cursor, bexcl, off, cursor);
    fill_kernel<<<(N_EDGES + 255) / 256, 256, 0, stream>>>(src, dst, cursor, csr_src);

    const int ggrid = (N_NODES * 64 + 255) / 256;  // one wave per node
    gather_kernel<<<ggrid, 256, 0, stream>>>(feats, off, csr_src, 0, D);
    gather_kernel<<<ggrid, 256, 0, stream>>>(feats, off, csr_src, D, 2 * D);

    gemm_mfma_kernel<<<(N_NODES + 127) / 128, 256, 0, stream>>>(feats, Wr, b, out);
}